// Round 1
// baseline (270.042 us; speedup 1.0000x reference)
//
#include <hip/hip_runtime.h>

// ---------------------------------------------------------------------------
// CrossSiloAggregator:
//   out = local_embeddings.copy()
//   for m in range(M):
//     r = idx[m]
//     w = sigmoid( dot(local[r], W[0:128]) + dot(foreign[m], W[128:256]) + b )
//     out[r] = w * local[r] + (1-w) * foreign[m]
//
// N_LOCAL = 1e6, M = 200k, D = 128. fp32 throughout. Memory-bound:
//   clone: 512 MB R + 512 MB W; blend: ~102 MB R(local rows) + ~102 MB
//   R(foreign) + ~102 MB W. Ideal ~1.33 GB -> ~211 us @ 6.3 TB/s.
// ---------------------------------------------------------------------------

#define DIM 128

// Kernel A: vectorized full-table clone (float4 grid-stride).
__global__ void clone_table_kernel(const float4* __restrict__ src,
                                   float4* __restrict__ dst,
                                   long long n4) {
    long long i = (long long)blockIdx.x * blockDim.x + threadIdx.x;
    long long stride = (long long)gridDim.x * blockDim.x;
    for (; i < n4; i += stride) {
        dst[i] = src[i];
    }
}

// Kernel B: one 64-lane wave per boundary row.
// Lane l owns elements [2l, 2l+1] of the 128-wide row (float2 = 8 B/lane,
// 512 B per wave-load -> fully coalesced).
__global__ void blend_scatter_kernel(const float* __restrict__ local_emb,
                                     const float* __restrict__ foreign_emb,
                                     const int* __restrict__ indices,
                                     const float* __restrict__ W_att,   // [256]
                                     const float* __restrict__ b_att,   // [1]
                                     float* __restrict__ out,
                                     int M) {
    const int wave_in_block = threadIdx.x >> 6;
    const int lane = threadIdx.x & 63;
    const int m = (blockIdx.x * (blockDim.x >> 6)) + wave_in_block;
    if (m >= M) return;

    const int row = indices[m];

    const float2 l = *(const float2*)(local_emb   + (long long)row * DIM + lane * 2);
    const float2 f = *(const float2*)(foreign_emb + (long long)m   * DIM + lane * 2);
    // W_att is [2*DIM, 1] flat: first 128 weights hit local, next 128 foreign.
    const float2 w0 = *(const float2*)(W_att       + lane * 2);
    const float2 w1 = *(const float2*)(W_att + DIM + lane * 2);

    float p = l.x * w0.x + l.y * w0.y + f.x * w1.x + f.y * w1.y;

    // Butterfly reduce across the full 64-lane wave.
    #pragma unroll
    for (int off = 32; off > 0; off >>= 1) {
        p += __shfl_xor(p, off);
    }

    const float s = 1.0f / (1.0f + __expf(-(p + b_att[0])));

    float2 o;
    o.x = s * l.x + (1.0f - s) * f.x;
    o.y = s * l.y + (1.0f - s) * f.y;
    *(float2*)(out + (long long)row * DIM + lane * 2) = o;
}

extern "C" void kernel_launch(void* const* d_in, const int* in_sizes, int n_in,
                              void* d_out, int out_size, void* d_ws, size_t ws_size,
                              hipStream_t stream) {
    const float* local_emb   = (const float*)d_in[0];
    const float* foreign_emb = (const float*)d_in[1];
    const int*   indices     = (const int*)d_in[2];
    const float* W_att       = (const float*)d_in[3];
    const float* b_att       = (const float*)d_in[4];
    float* out = (float*)d_out;

    const int M = in_sizes[1] / DIM;              // 200,000 foreign rows
    const long long n_total = (long long)out_size; // 1e6 * 128 floats
    const long long n4 = n_total / 4;

    // Kernel A: clone the full table into d_out.
    {
        const int block = 256;
        const int grid = 2048;  // grid-stride; ~8 blocks/CU territory
        clone_table_kernel<<<grid, block, 0, stream>>>(
            (const float4*)local_emb, (float4*)out, n4);
    }

    // Kernel B: blend + scatter the M boundary rows (overwrites clone rows;
    // stream ordering guarantees A completes first).
    {
        const int block = 256;                    // 4 waves/block
        const int waves_per_block = block / 64;
        const int grid = (M + waves_per_block - 1) / waves_per_block;
        blend_scatter_kernel<<<grid, block, 0, stream>>>(
            local_emb, foreign_emb, indices, W_att, b_att, out, M);
    }
}

// Round 2
// 242.489 us; speedup vs baseline: 1.1136x; 1.1136x over previous
//
#include <hip/hip_runtime.h>

// ---------------------------------------------------------------------------
// CrossSiloAggregator — fused single-pass version.
//   out[r] = blend(local[r], foreign[map[r]])  if map[r] >= 0
//          = local[r]                          otherwise
// where map is the inverse of `indices` (built per-call in d_ws).
//
// Traffic: 512 MB local R + 102 MB foreign R + 512 MB out W + ~9 MB map
//   ≈ 1.135 GB  ->  ~180 us @ 6.3 TB/s.
// (Previous 2-kernel scheme: 1.33 GB -> 270 us measured.)
// ---------------------------------------------------------------------------

#define DIM 128

__global__ void init_map_kernel(int* __restrict__ map, int n) {
    int i = blockIdx.x * blockDim.x + threadIdx.x;
    const int stride = gridDim.x * blockDim.x;
    for (; i < n; i += stride) map[i] = -1;
}

__global__ void scatter_map_kernel(const int* __restrict__ idx,
                                   int* __restrict__ map, int M) {
    int m = blockIdx.x * blockDim.x + threadIdx.x;
    const int stride = gridDim.x * blockDim.x;
    for (; m < M; m += stride) map[idx[m]] = m;
}

// One 32-lane half-wave per output row; lane owns a float4 (16 B) slice.
// 32 lanes x 16 B = 512 B per row, fully coalesced (1 KiB per wave since
// adjacent half-waves handle adjacent rows).
__global__ void fused_agg_kernel(const float* __restrict__ local_emb,
                                 const float* __restrict__ foreign_emb,
                                 const int* __restrict__ map,
                                 const float* __restrict__ W_att,   // [256]
                                 const float* __restrict__ b_att,   // [1]
                                 float* __restrict__ out,
                                 int n_rows) {
    const int lane32 = threadIdx.x & 31;

    // Per-lane attention weights are row-invariant: load once.
    const float4 w0 = *(const float4*)(W_att + lane32 * 4);
    const float4 w1 = *(const float4*)(W_att + DIM + lane32 * 4);
    const float bias = b_att[0];

    long long hw = ((long long)blockIdx.x * blockDim.x + threadIdx.x) >> 5;
    const long long hw_stride = ((long long)gridDim.x * blockDim.x) >> 5;

    for (long long row = hw; row < n_rows; row += hw_stride) {
        const float4 l = *(const float4*)(local_emb + row * DIM + lane32 * 4);
        const int fm = map[row];  // same addr across half-wave -> broadcast
        if (fm < 0) {
            *(float4*)(out + row * DIM + lane32 * 4) = l;
        } else {
            const float4 f =
                *(const float4*)(foreign_emb + (long long)fm * DIM + lane32 * 4);
            float p = l.x * w0.x + l.y * w0.y + l.z * w0.z + l.w * w0.w
                    + f.x * w1.x + f.y * w1.y + f.z * w1.z + f.w * w1.w;
            // Reduce within the 32-lane half-wave (offsets < 32 stay inside).
            #pragma unroll
            for (int off = 16; off > 0; off >>= 1) p += __shfl_xor(p, off);
            const float s = 1.0f / (1.0f + __expf(-(p + bias)));
            float4 o;
            o.x = s * l.x + (1.0f - s) * f.x;
            o.y = s * l.y + (1.0f - s) * f.y;
            o.z = s * l.z + (1.0f - s) * f.z;
            o.w = s * l.w + (1.0f - s) * f.w;
            *(float4*)(out + row * DIM + lane32 * 4) = o;
        }
    }
}

extern "C" void kernel_launch(void* const* d_in, const int* in_sizes, int n_in,
                              void* d_out, int out_size, void* d_ws, size_t ws_size,
                              hipStream_t stream) {
    const float* local_emb   = (const float*)d_in[0];
    const float* foreign_emb = (const float*)d_in[1];
    const int*   indices     = (const int*)d_in[2];
    const float* W_att       = (const float*)d_in[3];
    const float* b_att       = (const float*)d_in[4];
    float* out = (float*)d_out;

    const int M = in_sizes[1] / DIM;          // 200,000 foreign rows
    const int n_rows = out_size / DIM;        // 1,000,000 local rows

    int* map = (int*)d_ws;                    // n_rows ints (4 MB)

    // 1) map[r] = -1
    init_map_kernel<<<2048, 256, 0, stream>>>(map, n_rows);
    // 2) map[idx[m]] = m
    scatter_map_kernel<<<(M + 255) / 256, 256, 0, stream>>>(indices, map, M);
    // 3) fused copy/blend, one half-wave per row
    fused_agg_kernel<<<2048, 256, 0, stream>>>(
        local_emb, foreign_emb, map, W_att, b_att, out, n_rows);
}

// Round 4
// 208.091 us; speedup vs baseline: 1.2977x; 1.1653x over previous
//
#include <hip/hip_runtime.h>

// ---------------------------------------------------------------------------
// CrossSiloAggregator — fused single-pass, non-temporal, 2-row unroll.
//   out[r] = blend(local[r], foreign[map[r]])  if map[r] >= 0
//          = local[r]                          otherwise
//
// Traffic floor: 512 MB local R + 102 MB foreign R + 512 MB out W + ~9 MB map
//   ≈ 1.135 GB -> ~163-180 us at achieved fill/copy BW (6.3-6.9 TB/s).
// Round-2 measured 242 us (~4.9 TB/s): NT streams + 2-row unroll.
// NOTE: __builtin_nontemporal_* requires a true vector type, not
// HIP_vector_type — use ext_vector_type(4) float.
// ---------------------------------------------------------------------------

#define DIM 128

typedef float f4 __attribute__((ext_vector_type(4)));

__global__ void init_map_kernel(int* __restrict__ map, int n) {
    int i = blockIdx.x * blockDim.x + threadIdx.x;
    const int stride = gridDim.x * blockDim.x;
    for (; i < n; i += stride) map[i] = -1;
}

__global__ void scatter_map_kernel(const int* __restrict__ idx,
                                   int* __restrict__ map, int M) {
    int m = blockIdx.x * blockDim.x + threadIdx.x;
    const int stride = gridDim.x * blockDim.x;
    for (; m < M; m += stride) map[idx[m]] = m;
}

// One 32-lane half-wave per PAIR of consecutive rows; lane owns a float4
// (f4) slice of each. A wave64 touches 4 adjacent rows = 2 KB contiguous
// per load class. All bulk streams are non-temporal (no cache allocation).
__global__ void fused_agg_kernel(const float* __restrict__ local_emb,
                                 const float* __restrict__ foreign_emb,
                                 const int* __restrict__ map,
                                 const float* __restrict__ W_att,   // [256]
                                 const float* __restrict__ b_att,   // [1]
                                 float* __restrict__ out,
                                 int n_rows) {
    const int lane32 = threadIdx.x & 31;

    const f4 w0 = *(const f4*)(W_att + lane32 * 4);
    const f4 w1 = *(const f4*)(W_att + DIM + lane32 * 4);
    const float bias = b_att[0];

    const long long hw = ((long long)blockIdx.x * blockDim.x + threadIdx.x) >> 5;
    const long long hw_stride = ((long long)gridDim.x * blockDim.x) >> 5;

    for (long long r0 = hw * 2; r0 < n_rows; r0 += hw_stride * 2) {
        const long long r1 = r0 + 1;
        const bool has1 = (r1 < n_rows);

        // Issue all independent loads up front.
        const f4 l0 = __builtin_nontemporal_load(
            (const f4*)(local_emb + r0 * DIM + lane32 * 4));
        const int fm0 = map[r0];
        f4 l1 = {0.f, 0.f, 0.f, 0.f};
        int fm1 = -1;
        if (has1) {
            l1 = __builtin_nontemporal_load(
                (const f4*)(local_emb + r1 * DIM + lane32 * 4));
            fm1 = map[r1];
        }

        // Row 0
        if (fm0 < 0) {
            __builtin_nontemporal_store(l0, (f4*)(out + r0 * DIM + lane32 * 4));
        } else {
            const f4 f = __builtin_nontemporal_load(
                (const f4*)(foreign_emb + (long long)fm0 * DIM + lane32 * 4));
            float p = l0.x * w0.x + l0.y * w0.y + l0.z * w0.z + l0.w * w0.w
                    + f.x * w1.x + f.y * w1.y + f.z * w1.z + f.w * w1.w;
            #pragma unroll
            for (int off = 16; off > 0; off >>= 1) p += __shfl_xor(p, off);
            const float s = 1.0f / (1.0f + __expf(-(p + bias)));
            f4 o;
            o.x = s * l0.x + (1.0f - s) * f.x;
            o.y = s * l0.y + (1.0f - s) * f.y;
            o.z = s * l0.z + (1.0f - s) * f.z;
            o.w = s * l0.w + (1.0f - s) * f.w;
            __builtin_nontemporal_store(o, (f4*)(out + r0 * DIM + lane32 * 4));
        }

        // Row 1
        if (has1) {
            if (fm1 < 0) {
                __builtin_nontemporal_store(l1, (f4*)(out + r1 * DIM + lane32 * 4));
            } else {
                const f4 f = __builtin_nontemporal_load(
                    (const f4*)(foreign_emb + (long long)fm1 * DIM + lane32 * 4));
                float p = l1.x * w0.x + l1.y * w0.y + l1.z * w0.z + l1.w * w0.w
                        + f.x * w1.x + f.y * w1.y + f.z * w1.z + f.w * w1.w;
                #pragma unroll
                for (int off = 16; off > 0; off >>= 1) p += __shfl_xor(p, off);
                const float s = 1.0f / (1.0f + __expf(-(p + bias)));
                f4 o;
                o.x = s * l1.x + (1.0f - s) * f.x;
                o.y = s * l1.y + (1.0f - s) * f.y;
                o.z = s * l1.z + (1.0f - s) * f.z;
                o.w = s * l1.w + (1.0f - s) * f.w;
                __builtin_nontemporal_store(o, (f4*)(out + r1 * DIM + lane32 * 4));
            }
        }
    }
}

extern "C" void kernel_launch(void* const* d_in, const int* in_sizes, int n_in,
                              void* d_out, int out_size, void* d_ws, size_t ws_size,
                              hipStream_t stream) {
    const float* local_emb   = (const float*)d_in[0];
    const float* foreign_emb = (const float*)d_in[1];
    const int*   indices     = (const int*)d_in[2];
    const float* W_att       = (const float*)d_in[3];
    const float* b_att       = (const float*)d_in[4];
    float* out = (float*)d_out;

    const int M = in_sizes[1] / DIM;          // 200,000 foreign rows
    const int n_rows = out_size / DIM;        // 1,000,000 local rows

    int* map = (int*)d_ws;                    // n_rows ints (4 MB)

    init_map_kernel<<<2048, 256, 0, stream>>>(map, n_rows);
    scatter_map_kernel<<<(M + 255) / 256, 256, 0, stream>>>(indices, map, M);
    fused_agg_kernel<<<4096, 256, 0, stream>>>(
        local_emb, foreign_emb, map, W_att, b_att, out, n_rows);
}

// Round 5
// 201.863 us; speedup vs baseline: 1.3378x; 1.0309x over previous
//
#include <hip/hip_runtime.h>

// ---------------------------------------------------------------------------
// CrossSiloAggregator — fused single-pass, non-temporal, 4-row unroll.
//   out[r] = blend(local[r], foreign[map[r]])  if map[r] >= 0
//          = local[r]                          otherwise
//
// map init via hipMemsetAsync(0xFF) -> -1 (fast fill path, no extra kernel).
// Traffic floor ~1.13 GB -> ~180 us @ 6.3 TB/s copy ceiling.
// Round-4 measured 208 us (fused ~5.8 TB/s = 92% of copy ceiling).
// ---------------------------------------------------------------------------

#define DIM 128

typedef float f4 __attribute__((ext_vector_type(4)));
typedef int   i4 __attribute__((ext_vector_type(4)));

__global__ void scatter_map_kernel(const int* __restrict__ idx,
                                   int* __restrict__ map, int M) {
    int m = blockIdx.x * blockDim.x + threadIdx.x;
    const int stride = gridDim.x * blockDim.x;
    for (; m < M; m += stride) map[idx[m]] = m;
}

__device__ __forceinline__ void do_row(const float* __restrict__ foreign_emb,
                                       const float* __restrict__ out_base,
                                       float* __restrict__ out,
                                       long long row, int lane32, int fm,
                                       const f4& l, const f4& w0, const f4& w1,
                                       float bias) {
    if (fm < 0) {
        __builtin_nontemporal_store(l, (f4*)(out + row * DIM + lane32 * 4));
    } else {
        const f4 f = __builtin_nontemporal_load(
            (const f4*)(foreign_emb + (long long)fm * DIM + lane32 * 4));
        float p = l.x * w0.x + l.y * w0.y + l.z * w0.z + l.w * w0.w
                + f.x * w1.x + f.y * w1.y + f.z * w1.z + f.w * w1.w;
        #pragma unroll
        for (int off = 16; off > 0; off >>= 1) p += __shfl_xor(p, off);
        const float s = 1.0f / (1.0f + __expf(-(p + bias)));
        f4 o;
        o.x = s * l.x + (1.0f - s) * f.x;
        o.y = s * l.y + (1.0f - s) * f.y;
        o.z = s * l.z + (1.0f - s) * f.z;
        o.w = s * l.w + (1.0f - s) * f.w;
        __builtin_nontemporal_store(o, (f4*)(out + row * DIM + lane32 * 4));
    }
}

// One 32-lane half-wave per QUAD of consecutive rows; lane owns a float4
// slice of each. A wave64 touches 8 adjacent rows = 4 KB contiguous per
// stream. All bulk streams non-temporal. Map entries for the quad load as
// one broadcast int4.
__global__ void fused_agg_kernel(const float* __restrict__ local_emb,
                                 const float* __restrict__ foreign_emb,
                                 const int* __restrict__ map,
                                 const float* __restrict__ W_att,   // [256]
                                 const float* __restrict__ b_att,   // [1]
                                 float* __restrict__ out,
                                 int n_rows) {
    const int lane32 = threadIdx.x & 31;

    const f4 w0 = *(const f4*)(W_att + lane32 * 4);
    const f4 w1 = *(const f4*)(W_att + DIM + lane32 * 4);
    const float bias = b_att[0];

    const long long hw = ((long long)blockIdx.x * blockDim.x + threadIdx.x) >> 5;
    const long long hw_stride = ((long long)gridDim.x * blockDim.x) >> 5;

    const long long n_quads = n_rows >> 2;           // n_rows % 4 handled below

    for (long long q = hw; q < n_quads; q += hw_stride) {
        const long long r0 = q * 4;

        // All independent loads up front: 4 local f4 + 1 broadcast int4.
        const i4 fm = *(const i4*)(map + r0);
        const f4 l0 = __builtin_nontemporal_load(
            (const f4*)(local_emb + (r0 + 0) * DIM + lane32 * 4));
        const f4 l1 = __builtin_nontemporal_load(
            (const f4*)(local_emb + (r0 + 1) * DIM + lane32 * 4));
        const f4 l2 = __builtin_nontemporal_load(
            (const f4*)(local_emb + (r0 + 2) * DIM + lane32 * 4));
        const f4 l3 = __builtin_nontemporal_load(
            (const f4*)(local_emb + (r0 + 3) * DIM + lane32 * 4));

        do_row(foreign_emb, local_emb, out, r0 + 0, lane32, fm.x, l0, w0, w1, bias);
        do_row(foreign_emb, local_emb, out, r0 + 1, lane32, fm.y, l1, w0, w1, bias);
        do_row(foreign_emb, local_emb, out, r0 + 2, lane32, fm.z, l2, w0, w1, bias);
        do_row(foreign_emb, local_emb, out, r0 + 3, lane32, fm.w, l3, w0, w1, bias);
    }

    // Tail rows (n_rows % 4), handled by the first few half-waves.
    const long long tail_start = n_quads * 4;
    for (long long row = tail_start + hw; row < n_rows; row += hw_stride) {
        const int fm = map[row];
        const f4 l = __builtin_nontemporal_load(
            (const f4*)(local_emb + row * DIM + lane32 * 4));
        do_row(foreign_emb, local_emb, out, row, lane32, fm, l, w0, w1, bias);
    }
}

extern "C" void kernel_launch(void* const* d_in, const int* in_sizes, int n_in,
                              void* d_out, int out_size, void* d_ws, size_t ws_size,
                              hipStream_t stream) {
    const float* local_emb   = (const float*)d_in[0];
    const float* foreign_emb = (const float*)d_in[1];
    const int*   indices     = (const int*)d_in[2];
    const float* W_att       = (const float*)d_in[3];
    const float* b_att       = (const float*)d_in[4];
    float* out = (float*)d_out;

    const int M = in_sizes[1] / DIM;          // 200,000 foreign rows
    const int n_rows = out_size / DIM;        // 1,000,000 local rows

    int* map = (int*)d_ws;                    // n_rows ints (4 MB)

    // map[r] = -1 via byte-fill 0xFF (fast fill path, graph-capture safe).
    hipMemsetAsync(map, 0xFF, (size_t)n_rows * sizeof(int), stream);
    scatter_map_kernel<<<(M + 255) / 256, 256, 0, stream>>>(indices, map, M);
    fused_agg_kernel<<<4096, 256, 0, stream>>>(
        local_emb, foreign_emb, map, W_att, b_att, out, n_rows);
}